// Round 11
// baseline (1984.354 us; speedup 1.0000x reference)
//
#include <hip/hip_runtime.h>
#include <hip/hip_bf16.h>

typedef __attribute__((ext_vector_type(8))) short short8;
typedef __attribute__((ext_vector_type(4))) float f32x4;

#define THREADS 512
#define MFMA(a, b, c) __builtin_amdgcn_mfma_f32_16x16x32_bf16((a), (b), (c), 0, 0, 0)
#define WAITV(N) asm volatile("s_waitcnt vmcnt(" #N ")" ::: "memory")
#define WAITLG0() asm volatile("s_waitcnt lgkmcnt(0)" ::: "memory")

static __device__ __forceinline__ unsigned short f2bf(float x) {
    __hip_bfloat16 h = __float2bfloat16(x);
    return __builtin_bit_cast(unsigned short, h);
}
static __device__ __forceinline__ unsigned pk2(float a, float b) {
    return (unsigned)f2bf(a) | ((unsigned)f2bf(b) << 16);
}
static __device__ __forceinline__ float bflo(unsigned u) {
    unsigned v = u << 16; return __builtin_bit_cast(float, v);
}
static __device__ __forceinline__ float bfhi(unsigned u) {
    unsigned v = u & 0xffff0000u; return __builtin_bit_cast(float, v);
}
static __device__ __forceinline__ float fast_tanh(float x) {
    float e = __builtin_amdgcn_exp2f(x * 2.885390081777927f);
    float r = __builtin_amdgcn_rcpf(e + 1.0f);
    return fmaf(-2.0f, r, 1.0f);
}
static __device__ __forceinline__ short8 cvt8(float4 a, float4 b) {
    short8 r;
    r[0] = (short)f2bf(a.x); r[1] = (short)f2bf(a.y);
    r[2] = (short)f2bf(a.z); r[3] = (short)f2bf(a.w);
    r[4] = (short)f2bf(b.x); r[5] = (short)f2bf(b.y);
    r[6] = (short)f2bf(b.z); r[7] = (short)f2bf(b.w);
    return r;
}
static __device__ __forceinline__ void gl_lds16f(const float* g, float* l) {
    __builtin_amdgcn_global_load_lds(
        (const __attribute__((address_space(1))) unsigned int*)g,
        (__attribute__((address_space(3))) unsigned int*)l, 16, 0, 0);   // L2-cacheable
}

// Direct-load f32-B GEMM (R9-verified) — used for the small head GEMM only.
template<int NT, int NKT_S>
static __device__ __forceinline__ void gemm_f32B(
    const unsigned short* sfr, const float* __restrict__ Wsrc,
    f32x4 (&acc)[2][NT], const int w, const int l)
{
    const int q = l >> 4, c = l & 15;
    const float* bp = Wsrc + (size_t)(w * (NT * 16) + c) * 512 + q * 8;
    float4 fa[NT][2], fb[NT][2];
    #pragma unroll
    for (int nt = 0; nt < NT; ++nt) {
        fa[nt][0] = *(const float4*)(bp + nt * 8192);
        fa[nt][1] = *(const float4*)(bp + nt * 8192 + 4);
    }
    #pragma unroll
    for (int kt = 0; kt < NKT_S; ++kt) {
        if (kt + 1 < NKT_S) {
            #pragma unroll
            for (int nt = 0; nt < NT; ++nt) {
                fb[nt][0] = *(const float4*)(bp + nt * 8192 + (kt + 1) * 32);
                fb[nt][1] = *(const float4*)(bp + nt * 8192 + (kt + 1) * 32 + 4);
            }
        }
        short8 a0 = *(const short8*)(sfr + (kt * 64 + l) * 8);
        short8 a1 = *(const short8*)(sfr + ((16 + kt) * 64 + l) * 8);
        #pragma unroll
        for (int nt = 0; nt < NT; ++nt) {
            short8 b = cvt8(fa[nt][0], fa[nt][1]);
            acc[0][nt] = MFMA(a0, b, acc[0][nt]);
            acc[1][nt] = MFMA(a1, b, acc[1][nt]);
        }
        if (kt + 1 < NKT_S) {
            #pragma unroll
            for (int nt = 0; nt < NT; ++nt) { fa[nt][0] = fb[nt][0]; fa[nt][1] = fb[nt][1]; }
        }
    }
}

// Ring GEMM over 32 sub-chunks (sub = half-kt: 2 nt frags) streamed f32 from d_in.
// Slot layout (f32): slot*8192 + w*1024 + nt_loc*512 + h*256 + pos*4, with block
// position p holding W[rowgrp*8? -> row 8h+(p&7)][kchunk p>>3] (chunk = 4 floats).
// Staging instr (nt_loc,h): lane ls reads 16B at row (..+ls&7), chunk ls>>3 ->
// 8 full 128B lines per instr. Frag read lane l: addr f32 = base + (l&7)*4 +
// (l>>4)*64 (+32 for hi) -> bank quad = l&7 -> conflict-free b128.
// Invariant: 8 gl_lds outstanding at iter entry; stage sub c+2 (4 issues) then
// WAITV(8) = sub c resident. PHASE advances by 2 per step (32 % 3).
template<int PHASE, bool XPROJ>
static __device__ __forceinline__ void ring_gemm32(
    const unsigned short* sfr, float* ring,
    const float* __restrict__ Wh, const float* __restrict__ Wx,
    f32x4 (&acc)[2][4], const int w, const int l)
{
    const int r7 = l & 7;          // staging: row-in-group; read: bank row
    const int c8 = l >> 3;         // staging: k-chunk
    #pragma unroll
    for (int c = 0; c < 32; ++c) {
        const int kt = c >> 1, p = c & 1;
        const int slot  = (PHASE + c) % 3;
        const int cn    = (c + 2) & 31;
        const int ktn   = cn >> 1, pn = cn & 1;
        const int slotn = (PHASE + c + 2) % 3;
        const float* gsrc = (XPROJ && c < 30) ? Wx : Wh;
        // ---- stage sub c+2 (4 instrs; per-lane global src, lane-linear LDS dst) ----
        #pragma unroll
        for (int nt_loc = 0; nt_loc < 2; ++nt_loc)
            #pragma unroll
            for (int h = 0; h < 2; ++h)
                gl_lds16f(gsrc + (size_t)(w * 64 + (2 * pn + nt_loc) * 16 + h * 8 + r7) * 512
                               + ktn * 32 + c8 * 4,
                          ring + slotn * 8192 + w * 1024 + nt_loc * 512 + h * 256);
        WAITV(8);
        // ---- consume sub c ----
        short8 a0 = *(const short8*)(sfr + (kt * 64 + l) * 8);
        short8 a1 = *(const short8*)(sfr + ((16 + kt) * 64 + l) * 8);
        #pragma unroll
        for (int nt_loc = 0; nt_loc < 2; ++nt_loc) {
            const float* rp = ring + slot * 8192 + w * 1024 + nt_loc * 512
                            + ((l >> 3) & 1) * 256 + r7 * 4 + (l >> 4) * 64;
            float4 lo = *(const float4*)rp;
            float4 hi = *(const float4*)(rp + 32);
            short8 b = cvt8(lo, hi);
            const int nt = 2 * p + nt_loc;
            acc[0][nt] = MFMA(a0, b, acc[0][nt]);
            acc[1][nt] = MFMA(a1, b, acc[1][nt]);
        }
    }
}

static __device__ __forceinline__ void scatter_s(const float (&s)[2][4][4],
    unsigned short* sfrag, const int tIdx)
{
    #pragma unroll
    for (int mt = 0; mt < 2; ++mt)
        #pragma unroll
        for (int nt = 0; nt < 4; ++nt)
            #pragma unroll
            for (int i = 0; i < 4; ++i) {
                const int off = (mt * 16384 + (nt >> 1) * 1024 + ((2 * nt) & 3) * 256 + i * 16) >> 1;
                sfrag[tIdx + off] = f2bf(s[mt][nt][i]);
            }
}

template<int PHASE>
static __device__ __forceinline__ void do_step(
    float (&s)[2][4][4], unsigned (&hh)[3][2][4][2], const unsigned (&xpk)[2][4][2],
    unsigned short* sfrag, float* ring, const float* __restrict__ Wh,
    const int w, const int l, const int tIdx,
    const float g1, const float g2, const float g3)
{
    scatter_s(s, sfrag, tIdx);
    WAITLG0(); __builtin_amdgcn_s_barrier();     // raw barrier: DMA stays in flight

    f32x4 acc[2][4];
    #pragma unroll
    for (int mt = 0; mt < 2; ++mt)
        #pragma unroll
        for (int nt = 0; nt < 4; ++nt)
            acc[mt][nt] = (f32x4){0.f, 0.f, 0.f, 0.f};
    ring_gemm32<PHASE, false>(sfrag, ring, Wh, nullptr, acc, w, l);
    WAITLG0(); __builtin_amdgcn_s_barrier();     // all sfrag reads done before next scatter

    #pragma unroll
    for (int mt = 0; mt < 2; ++mt)
        #pragma unroll
        for (int nt = 0; nt < 4; ++nt)
            #pragma unroll
            for (int p = 0; p < 2; ++p) {
                unsigned u1 = hh[0][mt][nt][p];
                unsigned u2 = hh[1][mt][nt][p];
                unsigned u3 = hh[2][mt][nt][p];
                unsigned ux = xpk[mt][nt][p];
                float pre0 = acc[mt][nt][2 * p] + bflo(ux)
                           + g1 * bflo(u1) + g2 * bflo(u2) + g3 * bflo(u3);
                float pre1 = acc[mt][nt][2 * p + 1] + bfhi(ux)
                           + g1 * bfhi(u1) + g2 * bfhi(u2) + g3 * bfhi(u3);
                float so0 = s[mt][nt][2 * p], so1 = s[mt][nt][2 * p + 1];
                s[mt][nt][2 * p]     = 0.5f * so0 + 0.5f * fast_tanh(pre0);
                s[mt][nt][2 * p + 1] = 0.5f * so1 + 0.5f * fast_tanh(pre1);
                hh[2][mt][nt][p] = u2;           // lag shift (verified)
                hh[1][mt][nt][p] = u1;
                hh[0][mt][nt][p] = pk2(so0, so1);
            }
}

__global__ __attribute__((amdgpu_flat_work_group_size(512, 512), amdgpu_waves_per_eu(2, 2)))
void toroidal(
    const float* __restrict__ x,
    const float* __restrict__ Wx_w, const float* __restrict__ wxb,
    const float* __restrict__ Wh_w, const float* __restrict__ whb,
    const float* __restrict__ Hd_w, const float* __restrict__ hdb,
    const float* __restrict__ gamma_p, const float* __restrict__ alphas,
    const int* __restrict__ steps_p,
    float* __restrict__ out)
{
    __shared__ __align__(16) unsigned short sfrag[16384];   // 32 KB A-frags [mt2][kt16][lane64][e8]
    __shared__ __align__(16) float ring[3 * 8192];          // 96 KB f32 staging ring

    const int tid = threadIdx.x;
    const int w = tid >> 6;
    const int l = tid & 63;
    const int q = l >> 4;
    const int c = l & 15;
    const int rbase = blockIdx.x * 32;

    // all scalar/bias loads BEFORE the vmcnt baseline reset
    const float gm = gamma_p[0];
    const float g1 = gm * alphas[0], g2 = gm * alphas[1], g3 = gm * alphas[2];
    const int nsteps = steps_p[0];
    float bsum[4];
    #pragma unroll
    for (int nt = 0; nt < 4; ++nt) {
        int col = w * 64 + nt * 16 + c;
        bsum[nt] = wxb[col] + whb[col];
    }
    const float hb0 = hdb[w * 32 + c], hb1 = hdb[w * 32 + 16 + c];

    // pack x tile (32 rows) into sfrag as bf16 A-frags (verified)
    #pragma unroll
    for (int j = 0; j < 4; ++j) {
        int f = tid + j * THREADS;                 // [0, 2048)
        int mt = f >> 10;
        int kt = (f >> 6) & 15;
        int lf = f & 63;
        int row = mt * 16 + (lf & 15);
        int k0  = kt * 32 + (lf >> 4) * 8;
        const float* sp = x + (size_t)(rbase + row) * 512 + k0;
        float4 a = *(const float4*)sp;
        float4 b = *(const float4*)(sp + 4);
        uint4 o;
        o.x = pk2(a.x, a.y); o.y = pk2(a.z, a.w);
        o.z = pk2(b.x, b.y); o.w = pk2(b.z, b.w);
        *(uint4*)(sfrag + (size_t)f * 8) = o;
    }
    __syncthreads();    // drains vmcnt -> clean baseline for counted ring waits

    {   // prologue: stage Wx subs 0,1
        const int r7 = l & 7, c8 = l >> 3;
        #pragma unroll
        for (int cc = 0; cc < 2; ++cc)
            #pragma unroll
            for (int nt_loc = 0; nt_loc < 2; ++nt_loc)
                #pragma unroll
                for (int h = 0; h < 2; ++h)
                    gl_lds16f(Wx_w + (size_t)(w * 64 + (2 * (cc & 1) + nt_loc) * 16 + h * 8 + r7) * 512
                                   + (cc >> 1) * 32 + c8 * 4,
                              ring + cc * 8192 + w * 1024 + nt_loc * 512 + h * 256);
    }

    // xproj via ring (tail stages Wh subs 0,1)
    f32x4 acc[2][4];
    #pragma unroll
    for (int mt = 0; mt < 2; ++mt)
        #pragma unroll
        for (int nt = 0; nt < 4; ++nt)
            acc[mt][nt] = (f32x4){0.f, 0.f, 0.f, 0.f};
    ring_gemm32<0, true>(sfrag, ring, Wh_w, Wx_w, acc, w, l);

    unsigned xpk[2][4][2];
    #pragma unroll
    for (int mt = 0; mt < 2; ++mt)
        #pragma unroll
        for (int nt = 0; nt < 4; ++nt) {
            float b = bsum[nt];
            xpk[mt][nt][0] = pk2(acc[mt][nt][0] + b, acc[mt][nt][1] + b);
            xpk[mt][nt][1] = pk2(acc[mt][nt][2] + b, acc[mt][nt][3] + b);
        }
    WAITLG0(); __builtin_amdgcn_s_barrier();   // xproj sfrag reads done; DMA in flight

    float s[2][4][4];
    unsigned hh[3][2][4][2];
    #pragma unroll
    for (int mt = 0; mt < 2; ++mt)
        #pragma unroll
        for (int nt = 0; nt < 4; ++nt) {
            #pragma unroll
            for (int i = 0; i < 4; ++i) s[mt][nt][i] = 0.f;
            #pragma unroll
            for (int a = 0; a < 3; ++a) { hh[a][mt][nt][0] = 0u; hh[a][mt][nt][1] = 0u; }
        }

    const int tIdx = (w * 2048 + q * 64 + (l & 7) * 2 + (((l >> 3) & 1) << 8)) >> 1;

    // step t uses PHASE = (2t)%3: pattern 2,1,0 repeating
    int t = 0;
    while (t + 3 <= nsteps) {
        do_step<2>(s, hh, xpk, sfrag, ring, Wh_w, w, l, tIdx, g1, g2, g3);
        do_step<1>(s, hh, xpk, sfrag, ring, Wh_w, w, l, tIdx, g1, g2, g3);
        do_step<0>(s, hh, xpk, sfrag, ring, Wh_w, w, l, tIdx, g1, g2, g3);
        t += 3;
    }
    if (t < nsteps) { do_step<2>(s, hh, xpk, sfrag, ring, Wh_w, w, l, tIdx, g1, g2, g3); ++t; }
    if (t < nsteps) { do_step<1>(s, hh, xpk, sfrag, ring, Wh_w, w, l, tIdx, g1, g2, g3); ++t; }

    // ================= head: out = s_final @ Head^T + Head_b =================
    scatter_s(s, sfrag, tIdx);
    WAITLG0(); __builtin_amdgcn_s_barrier();
    WAITV(0);           // drain leftover step stages

    f32x4 acch[2][2];
    #pragma unroll
    for (int mt = 0; mt < 2; ++mt)
        #pragma unroll
        for (int nt = 0; nt < 2; ++nt)
            acch[mt][nt] = (f32x4){0.f, 0.f, 0.f, 0.f};
    gemm_f32B<2, 16>(sfrag, Hd_w, acch, w, l);

    #pragma unroll
    for (int nt = 0; nt < 2; ++nt) {
        int col = w * 32 + nt * 16 + c;
        float hb = nt ? hb1 : hb0;
        #pragma unroll
        for (int mt = 0; mt < 2; ++mt)
            #pragma unroll
            for (int i = 0; i < 4; ++i)
                out[(size_t)(rbase + mt * 16 + q * 4 + i) * 256 + col] = acch[mt][nt][i] + hb;
    }
}

extern "C" void kernel_launch(void* const* d_in, const int* in_sizes, int n_in,
                              void* d_out, int out_size, void* d_ws, size_t ws_size,
                              hipStream_t stream) {
    (void)n_in; (void)out_size; (void)d_ws; (void)ws_size;
    const float* x    = (const float*)d_in[0];
    const float* Wx_w = (const float*)d_in[1];
    const float* Wx_b = (const float*)d_in[2];
    const float* Wh_w = (const float*)d_in[3];
    const float* Wh_b = (const float*)d_in[4];
    const float* Hd_w = (const float*)d_in[5];
    const float* Hd_b = (const float*)d_in[6];
    const float* gma  = (const float*)d_in[7];
    const float* alp  = (const float*)d_in[8];
    const int*   stp  = (const int*)d_in[9];
    float* out = (float*)d_out;

    int batch = in_sizes[0] / 512;                 // 8192
    int nblk  = batch / 32;                        // 256 blocks, 1 per CU
    toroidal<<<nblk, THREADS, 0, stream>>>(x, Wx_w, Wx_b, Wh_w, Wh_b, Hd_w, Hd_b,
                                           gma, alp, stp, out);
}

// Round 12
// 562.688 us; speedup vs baseline: 3.5266x; 3.5266x over previous
//
#include <hip/hip_runtime.h>
#include <hip/hip_bf16.h>

typedef __attribute__((ext_vector_type(8))) short short8;
typedef __attribute__((ext_vector_type(4))) float f32x4;

#define THREADS 512
#define MFMA(a, b, c) __builtin_amdgcn_mfma_f32_16x16x32_bf16((a), (b), (c), 0, 0, 0)

static __device__ __forceinline__ unsigned short f2bf(float x) {
    __hip_bfloat16 h = __float2bfloat16(x);
    return __builtin_bit_cast(unsigned short, h);
}
static __device__ __forceinline__ unsigned pk2(float a, float b) {
    return (unsigned)f2bf(a) | ((unsigned)f2bf(b) << 16);
}
static __device__ __forceinline__ float bflo(unsigned u) {
    unsigned v = u << 16; return __builtin_bit_cast(float, v);
}
static __device__ __forceinline__ float bfhi(unsigned u) {
    unsigned v = u & 0xffff0000u; return __builtin_bit_cast(float, v);
}
static __device__ __forceinline__ float fast_tanh(float x) {
    float e = __builtin_amdgcn_exp2f(x * 2.885390081777927f);
    float r = __builtin_amdgcn_rcpf(e + 1.0f);
    return fmaf(-2.0f, r, 1.0f);
}
static __device__ __forceinline__ short8 cvt8(float4 a, float4 b) {
    short8 r;
    r[0] = (short)f2bf(a.x); r[1] = (short)f2bf(a.y);
    r[2] = (short)f2bf(a.z); r[3] = (short)f2bf(a.w);
    r[4] = (short)f2bf(b.x); r[5] = (short)f2bf(b.y);
    r[6] = (short)f2bf(b.z); r[7] = (short)f2bf(b.w);
    return r;
}

// Panel: 32 cols x 512 k bf16 in registers (AGPR-resident, R8-proven), natural kt order.
// B-frag (verified): lane holds W[CB + nt*16 + (l&15)][kt*32 + (l>>4)*8 + e]
#define LOAD_PANEL(W, CB)                                                       \
    do {                                                                        \
        _Pragma("unroll")                                                       \
        for (int j = 0; j < 16; ++j) {                                          \
            const float* p0_ = (W) + (size_t)((CB) + c) * 512 + j * 32 + q * 8;       \
            const float* p1_ = (W) + (size_t)((CB) + 16 + c) * 512 + j * 32 + q * 8;  \
            float4 a0_ = *(const float4*)p0_, b0_ = *(const float4*)(p0_ + 4);  \
            float4 a1_ = *(const float4*)p1_, b1_ = *(const float4*)(p1_ + 4);  \
            bw0[j] = cvt8(a0_, b0_);                                            \
            bw1[j] = cvt8(a1_, b1_);                                            \
        }                                                                       \
    } while (0)

// Fused GEMM over K: nt 0,1 from register panel; nt 2,3 streamed f32 from d_in
// (L2-cacheable) with a 1-kt lookahead in named regs (4 dwordx4 in flight/wave).
static __device__ __forceinline__ void fused_gemm(
    const unsigned short* sfr, const float* __restrict__ gstream,
    const short8 (&bw0)[16], const short8 (&bw1)[16],
    f32x4 (&acc)[2][4], const int w, const int l)
{
    const int q = l >> 4;
    const float* gp = gstream + (size_t)(w * 64 + 32 + (l & 15)) * 512 + q * 8;
    float4 A0, A1, A2, A3, B0, B1, B2, B3;
    A0 = *(const float4*)(gp);
    A1 = *(const float4*)(gp + 4);
    A2 = *(const float4*)(gp + 8192);
    A3 = *(const float4*)(gp + 8196);
    B0 = A0; B1 = A1; B2 = A2; B3 = A3;   // init (dead, keeps defs simple)
    #pragma unroll
    for (int kt = 0; kt < 16; ++kt) {
        if (kt < 15) {                     // issue kt+1 into the other buffer
            const float* gn = gp + (kt + 1) * 32;
            if ((kt & 1) == 0) {
                B0 = *(const float4*)(gn);        B1 = *(const float4*)(gn + 4);
                B2 = *(const float4*)(gn + 8192); B3 = *(const float4*)(gn + 8196);
            } else {
                A0 = *(const float4*)(gn);        A1 = *(const float4*)(gn + 4);
                A2 = *(const float4*)(gn + 8192); A3 = *(const float4*)(gn + 8196);
            }
        }
        short8 a0 = *(const short8*)(sfr + (kt * 64 + l) * 8);
        short8 a1 = *(const short8*)(sfr + ((16 + kt) * 64 + l) * 8);
        acc[0][0] = MFMA(a0, bw0[kt], acc[0][0]);
        acc[1][0] = MFMA(a1, bw0[kt], acc[1][0]);
        acc[0][1] = MFMA(a0, bw1[kt], acc[0][1]);
        acc[1][1] = MFMA(a1, bw1[kt], acc[1][1]);
        short8 b2, b3;
        if ((kt & 1) == 0) { b2 = cvt8(A0, A1); b3 = cvt8(A2, A3); }
        else               { b2 = cvt8(B0, B1); b3 = cvt8(B2, B3); }
        acc[0][2] = MFMA(a0, b2, acc[0][2]);
        acc[1][2] = MFMA(a1, b2, acc[1][2]);
        acc[0][3] = MFMA(a0, b3, acc[0][3]);
        acc[1][3] = MFMA(a1, b3, acc[1][3]);
    }
}

// Direct-load f32-B GEMM (R9-verified) — head only.
template<int NT, int NKT_S>
static __device__ __forceinline__ void gemm_f32B(
    const unsigned short* sfr, const float* __restrict__ Wsrc,
    f32x4 (&acc)[2][NT], const int w, const int l)
{
    const int q = l >> 4, c = l & 15;
    const float* bp = Wsrc + (size_t)(w * (NT * 16) + c) * 512 + q * 8;
    float4 fa[NT][2], fb[NT][2];
    #pragma unroll
    for (int nt = 0; nt < NT; ++nt) {
        fa[nt][0] = *(const float4*)(bp + nt * 8192);
        fa[nt][1] = *(const float4*)(bp + nt * 8192 + 4);
    }
    #pragma unroll
    for (int kt = 0; kt < NKT_S; ++kt) {
        if (kt + 1 < NKT_S) {
            #pragma unroll
            for (int nt = 0; nt < NT; ++nt) {
                fb[nt][0] = *(const float4*)(bp + nt * 8192 + (kt + 1) * 32);
                fb[nt][1] = *(const float4*)(bp + nt * 8192 + (kt + 1) * 32 + 4);
            }
        }
        short8 a0 = *(const short8*)(sfr + (kt * 64 + l) * 8);
        short8 a1 = *(const short8*)(sfr + ((16 + kt) * 64 + l) * 8);
        #pragma unroll
        for (int nt = 0; nt < NT; ++nt) {
            short8 b = cvt8(fa[nt][0], fa[nt][1]);
            acc[0][nt] = MFMA(a0, b, acc[0][nt]);
            acc[1][nt] = MFMA(a1, b, acc[1][nt]);
        }
        if (kt + 1 < NKT_S) {
            #pragma unroll
            for (int nt = 0; nt < NT; ++nt) { fa[nt][0] = fb[nt][0]; fa[nt][1] = fb[nt][1]; }
        }
    }
}

static __device__ __forceinline__ void scatter_s(const float (&s)[2][4][4],
    unsigned short* sfrag, const int tIdx)
{
    #pragma unroll
    for (int mt = 0; mt < 2; ++mt)
        #pragma unroll
        for (int nt = 0; nt < 4; ++nt)
            #pragma unroll
            for (int i = 0; i < 4; ++i) {
                const int off = (mt * 16384 + (nt >> 1) * 1024 + ((2 * nt) & 3) * 256 + i * 16) >> 1;
                sfrag[tIdx + off] = f2bf(s[mt][nt][i]);
            }
}

// one recurrence step; SA = t&1 (R3-R8-verified lag structure: h0 = s_{t-2},
// hist[SA] = s_{t-3}, hist[SA^1] = s_{t-4}; nB (=u1) -> hist[SA^1]; h0 <- s_{t-1})
template<int SA>
static __device__ __forceinline__ void do_step(
    float (&s)[2][4][4], unsigned (&h0)[2][4][2], f32x4 (&acc)[2][4],
    unsigned short* sfrag, unsigned* histu, const unsigned* xpl,
    const float* __restrict__ Wh_w,
    const short8 (&bw0)[16], const short8 (&bw1)[16],
    const int w, const int l, const int tid, const int tIdx,
    const float g1, const float g2, const float g3)
{
    scatter_s(s, sfrag, tIdx);
    __syncthreads();
    fused_gemm(sfrag, Wh_w, bw0, bw1, acc, w, l);
    __syncthreads();

    const int sB = SA ^ 1;
    #pragma unroll
    for (int mt = 0; mt < 2; ++mt)
        #pragma unroll
        for (int g = 0; g < 2; ++g) {
            uint4 hA = *(uint4*)&histu[((SA * 2 + mt) * 512 + tid) * 8 + g * 4];
            uint4 hB = *(uint4*)&histu[((sB * 2 + mt) * 512 + tid) * 8 + g * 4];
            uint4 nB;
            #pragma unroll
            for (int ntl = 0; ntl < 2; ++ntl) {
                const int nt = g * 2 + ntl;
                #pragma unroll
                for (int p = 0; p < 2; ++p) {
                    unsigned u1 = h0[mt][nt][p];
                    unsigned u2 = ((unsigned*)&hA)[ntl * 2 + p];
                    unsigned u3 = ((unsigned*)&hB)[ntl * 2 + p];
                    unsigned ux = xpl[tid * 16 + mt * 8 + nt * 2 + p];
                    float pre0 = acc[mt][nt][2 * p] + bflo(ux)
                               + g1 * bflo(u1) + g2 * bflo(u2) + g3 * bflo(u3);
                    float pre1 = acc[mt][nt][2 * p + 1] + bfhi(ux)
                               + g1 * bfhi(u1) + g2 * bfhi(u2) + g3 * bfhi(u3);
                    float so0 = s[mt][nt][2 * p], so1 = s[mt][nt][2 * p + 1];
                    s[mt][nt][2 * p]     = 0.5f * so0 + 0.5f * fast_tanh(pre0);
                    s[mt][nt][2 * p + 1] = 0.5f * so1 + 0.5f * fast_tanh(pre1);
                    ((unsigned*)&nB)[ntl * 2 + p] = u1;     // s_{t-2} -> becomes s_{t'-4}
                    h0[mt][nt][p] = pk2(so0, so1);          // s_{t-1} for next step
                }
            }
            *(uint4*)&histu[((sB * 2 + mt) * 512 + tid) * 8 + g * 4] = nB;
            acc[mt][g * 2 + 0] = (f32x4){0.f, 0.f, 0.f, 0.f};
            acc[mt][g * 2 + 1] = (f32x4){0.f, 0.f, 0.f, 0.f};
        }
}

__global__ __attribute__((amdgpu_flat_work_group_size(512, 512), amdgpu_waves_per_eu(2, 2)))
void toroidal(
    const float* __restrict__ x,
    const float* __restrict__ Wx_w, const float* __restrict__ wxb,
    const float* __restrict__ Wh_w, const float* __restrict__ whb,
    const float* __restrict__ Hd_w, const float* __restrict__ hdb,
    const float* __restrict__ gamma_p, const float* __restrict__ alphas,
    const int* __restrict__ steps_p,
    float* __restrict__ out)
{
    __shared__ __align__(16) unsigned short sfrag[16384];     // 32 KB A-frags [mt2][kt16][lane64][e8]
    __shared__ __align__(16) unsigned histu[2 * 2 * 512 * 8]; // 64 KB hist: [slot2][mt2][tid][8 u32]
    __shared__ __align__(16) unsigned xpl[512 * 16];          // 32 KB xproj packed bf16 pairs

    const int tid = threadIdx.x;
    const int w = tid >> 6;
    const int l = tid & 63;
    const int q = l >> 4;
    const int c = l & 15;
    const int rbase = blockIdx.x * 32;

    const float gm = gamma_p[0];
    const float g1 = gm * alphas[0], g2 = gm * alphas[1], g3 = gm * alphas[2];
    const int nsteps = steps_p[0];

    // ---- pack x tile (32 rows) into sfrag as bf16 A-frags (verified) ----
    #pragma unroll
    for (int j = 0; j < 4; ++j) {
        int f = tid + j * THREADS;                 // [0, 2048)
        int mt = f >> 10;
        int kt = (f >> 6) & 15;
        int lf = f & 63;
        int row = mt * 16 + (lf & 15);
        int k0  = kt * 32 + (lf >> 4) * 8;
        const float* sp = x + (size_t)(rbase + row) * 512 + k0;
        float4 a = *(const float4*)sp;
        float4 b = *(const float4*)(sp + 4);
        short8 v = cvt8(a, b);
        *(short8*)&sfrag[(size_t)f * 8] = v;
    }
    __syncthreads();

    short8 bw0[16], bw1[16];
    f32x4 acc[2][4];
    #pragma unroll
    for (int mt = 0; mt < 2; ++mt)
        #pragma unroll
        for (int nt = 0; nt < 4; ++nt)
            acc[mt][nt] = (f32x4){0.f, 0.f, 0.f, 0.f};

    // ---- xproj: panel <- Wx (cols w*64..+32), stream Wx cols +32..+64 ----
    LOAD_PANEL(Wx_w, w * 64);
    fused_gemm(sfrag, Wx_w, bw0, bw1, acc, w, l);

    #pragma unroll
    for (int mt = 0; mt < 2; ++mt)
        #pragma unroll
        for (int nt = 0; nt < 4; ++nt) {
            int col = w * 64 + nt * 16 + c;
            float b = wxb[col] + whb[col];
            xpl[tid * 16 + mt * 8 + nt * 2 + 0] = pk2(acc[mt][nt][0] + b, acc[mt][nt][1] + b);
            xpl[tid * 16 + mt * 8 + nt * 2 + 1] = pk2(acc[mt][nt][2] + b, acc[mt][nt][3] + b);
            acc[mt][nt] = (f32x4){0.f, 0.f, 0.f, 0.f};
        }

    // ---- panel <- Wh; zero hist/state ----
    LOAD_PANEL(Wh_w, w * 64);
    uint4 z4 = {0u, 0u, 0u, 0u};
    #pragma unroll
    for (int sb = 0; sb < 8; ++sb) *(uint4*)&histu[(sb * 512 + tid) * 4] = z4;
    float s[2][4][4];
    unsigned h0[2][4][2];
    #pragma unroll
    for (int mt = 0; mt < 2; ++mt)
        #pragma unroll
        for (int nt = 0; nt < 4; ++nt) {
            #pragma unroll
            for (int i = 0; i < 4; ++i) s[mt][nt][i] = 0.f;
            h0[mt][nt][0] = h0[mt][nt][1] = 0u;
        }
    __syncthreads();   // xproj sfrag reads + hist zero complete before step-1 scatter

    const int tIdx = (w * 2048 + q * 64 + (l & 7) * 2 + (((l >> 3) & 1) << 8)) >> 1;

    // ---- recurrence ----
    int t = 1;
    for (; t + 1 <= nsteps; t += 2) {
        do_step<1>(s, h0, acc, sfrag, histu, xpl, Wh_w, bw0, bw1, w, l, tid, tIdx, g1, g2, g3);
        do_step<0>(s, h0, acc, sfrag, histu, xpl, Wh_w, bw0, bw1, w, l, tid, tIdx, g1, g2, g3);
    }
    if (t <= nsteps)
        do_step<1>(s, h0, acc, sfrag, histu, xpl, Wh_w, bw0, bw1, w, l, tid, tIdx, g1, g2, g3);

    // ---- head: out = s_final @ Head^T + Head_b (R9-verified direct stream) ----
    scatter_s(s, sfrag, tIdx);
    __syncthreads();

    f32x4 acch[2][2];
    #pragma unroll
    for (int mt = 0; mt < 2; ++mt)
        #pragma unroll
        for (int nt = 0; nt < 2; ++nt)
            acch[mt][nt] = (f32x4){0.f, 0.f, 0.f, 0.f};
    gemm_f32B<2, 16>(sfrag, Hd_w, acch, w, l);

    const float hb0 = hdb[w * 32 + c], hb1 = hdb[w * 32 + 16 + c];
    #pragma unroll
    for (int nt = 0; nt < 2; ++nt) {
        int col = w * 32 + nt * 16 + c;            // 8 waves x 32 = 256 cols
        float hb = nt ? hb1 : hb0;
        #pragma unroll
        for (int mt = 0; mt < 2; ++mt)
            #pragma unroll
            for (int i = 0; i < 4; ++i)
                out[(size_t)(rbase + mt * 16 + q * 4 + i) * 256 + col] = acch[mt][nt][i] + hb;
    }
}

extern "C" void kernel_launch(void* const* d_in, const int* in_sizes, int n_in,
                              void* d_out, int out_size, void* d_ws, size_t ws_size,
                              hipStream_t stream) {
    (void)n_in; (void)out_size; (void)d_ws; (void)ws_size;
    const float* x    = (const float*)d_in[0];
    const float* Wx_w = (const float*)d_in[1];
    const float* Wx_b = (const float*)d_in[2];
    const float* Wh_w = (const float*)d_in[3];
    const float* Wh_b = (const float*)d_in[4];
    const float* Hd_w = (const float*)d_in[5];
    const float* Hd_b = (const float*)d_in[6];
    const float* gma  = (const float*)d_in[7];
    const float* alp  = (const float*)d_in[8];
    const int*   stp  = (const int*)d_in[9];
    float* out = (float*)d_out;

    int batch = in_sizes[0] / 512;                 // 8192
    int nblk  = batch / 32;                        // 256 blocks, 1 per CU
    toroidal<<<nblk, THREADS, 0, stream>>>(x, Wx_w, Wx_b, Wh_w, Wh_b, Hd_w, Hd_b,
                                           gma, alp, stp, out);
}